// Round 3
// baseline (536.275 us; speedup 1.0000x reference)
//
#include <hip/hip_runtime.h>

#define NB 2
#define NN 512
#define NC 256
#define OUTP 14
#define SS 28
#define CH_SPLIT 4
#define CH_PER_BLK (NC / CH_SPLIT)                     // 64
#define ELEMS_PER_BLK (CH_PER_BLK * OUTP * OUTP)       // 12544
#define POOL_PER_BOX (NC * OUTP * OUTP)                // 50176
#define POOL_TOTAL (NB * NN * POOL_PER_BOX)
#define BOX_OFF POOL_TOTAL
#define KEEP_OFF (POOL_TOTAL + NB * NN * 4)

// K2 staging geometry: GCH channels per group, double-buffered.
// cells = PW*PH <= (0.9643*u+2)(0.9643*v+2), uv<=784, u<=128  ->  <= ~992.
// I = ceil(cells/256) <= 4; tail lanes write dst[i] for i < I*256 <= 1023 < PATCH_MAX.
#define GCH 4
#define NGRP (CH_PER_BLK / GCH)    // 16
#define PATCH_MAX 1256             // 2*4*1256*4 B = 40192 B + tables = 40.6 KB -> 4 blocks/CU

typedef const __attribute__((address_space(1))) unsigned int GU32;
typedef __attribute__((address_space(3))) unsigned int LU32;

// ---------------- K1: fused NMS (sort + suppression matrix + greedy), one block per batch ----
__global__ __launch_bounds__(512) void k_nms(const float* __restrict__ boxes,
                                             const float* __restrict__ scores,
                                             float* __restrict__ dout) {
    int b = blockIdx.x;
    int tid = threadIdx.x;
    __shared__ float sS[NN];
    __shared__ int sI[NN];
    __shared__ float4 sB[NN];
    __shared__ float sA[NN];
    __shared__ int sL[NN];
    __shared__ unsigned long long sup[NN][8];   // 32 KB
    __shared__ unsigned long long skw[8];
    __shared__ int korig[NN];

    sS[tid] = scores[b * NN + tid];
    sI[tid] = tid;
    __syncthreads();
    for (int k = 2; k <= NN; k <<= 1) {
        for (int j = k >> 1; j > 0; j >>= 1) {
            int ixj = tid ^ j;
            if (ixj > tid) {
                float s1 = sS[tid], s2 = sS[ixj];
                int i1 = sI[tid], i2 = sI[ixj];
                bool lt = (s1 > s2) || (s1 == s2 && i1 < i2);
                bool up = ((tid & k) == 0);
                if (up ? !lt : lt) {
                    sS[tid] = s2; sS[ixj] = s1;
                    sI[tid] = i2; sI[ixj] = i1;
                }
            }
            __syncthreads();
        }
    }
    {
        int o = sI[tid];
        float4 bx = ((const float4*)boxes)[b * NN + o];
        float w = bx.z, h = bx.w;
        float x1 = bx.x - w * 0.5f, y1 = bx.y - h * 0.5f;
        float x2 = bx.x + w * 0.5f, y2 = bx.y + h * 0.5f;
        float s = sqrtf(w * h);
        int lvl = (s < 112.f) ? 1 : ((s < 224.f) ? 2 : ((s < 448.f) ? 3 : 4));
        sB[tid] = make_float4(x1, y1, x2, y2);
        sA[tid] = (x2 - x1) * (y2 - y1);
        sL[tid] = lvl;
    }
    __syncthreads();
    {
        float4 bi = sB[tid];
        float areai = sA[tid];
        int il = sL[tid];
        for (int cg = 0; cg < 8; ++cg) {
            unsigned long long m = 0ull;
            int jb = cg << 6;
#pragma unroll 4
            for (int k = 0; k < 64; ++k) {
                int j = jb + k;
                float4 bj = sB[j];
                float xx1 = fmaxf(bi.x, bj.x);
                float yy1 = fmaxf(bi.y, bj.y);
                float xx2 = fminf(bi.z, bj.z);
                float yy2 = fminf(bi.w, bj.w);
                float inter = fmaxf(xx2 - xx1, 0.0f) * fmaxf(yy2 - yy1, 0.0f);
                float denom = areai + sA[j] - inter + 1e-9f;
                bool sp = (j > tid) && (sL[j] == il) && ((inter / denom) > 0.5f);
                m |= sp ? (1ull << k) : 0ull;
            }
            sup[tid][cg] = m;
        }
    }
    __syncthreads();
    if (tid < 64) {
        int myw = tid & 7;
        unsigned long long kwl = ~0ull;
        for (int w = 0; w < 8; ++w) {
            unsigned long long aw = __shfl(kwl, w);
            int ibase = w << 6;
            for (int bb = 0; bb < 64; ++bb) {
                int i = ibase + bb;
                unsigned long long rw = sup[i][w];
                unsigned long long rl = sup[i][myw];
                if ((aw >> bb) & 1ull) {
                    aw &= ~rw;
                    kwl &= ~rl;
                }
            }
        }
        if (tid < 8) skw[tid] = kwl;
    }
    __syncthreads();
    korig[sI[tid]] = (int)((skw[tid >> 6] >> (tid & 63)) & 1ull);
    __syncthreads();
    {
        float4 bx = ((const float4*)boxes)[b * NN + tid];
        float kf = korig[tid] ? 1.0f : 0.0f;
        float x1 = (bx.x - bx.z * 0.5f) * kf;
        float y1 = (bx.y - bx.w * 0.5f) * kf;
        float x2 = (bx.x + bx.z * 0.5f) * kf;
        float y2 = (bx.y + bx.w * 0.5f) * kf;
        ((float4*)(dout + BOX_OFF))[b * NN + tid] = make_float4(x1, y1, x2, y2);
        dout[KEEP_OFF + b * NN + tid] = kf;
    }
}

// ---------------- K2: ROI align, async-staged + double-buffered + ds_read2-friendly ----------
// Per (box, 64-ch chunk) block. 16 groups of 4 channels:
//   STAGE(g+1) via global_load_lds (async, no VGPR round trip)
//   s_waitcnt vmcnt(4*I) (counted: next group's loads stay in flight) ; raw s_barrier
//   COMPUTE(g): bilinear with guaranteed-adjacent corners -> ds_read2_b32 pairs
//   raw s_barrier (protect buffer about to be overwritten)
__global__ __launch_bounds__(256, 4) void k_roi(const float* __restrict__ p4,
                                                const float* __restrict__ p8,
                                                const float* __restrict__ p16,
                                                const float* __restrict__ p32,
                                                const float* __restrict__ boxes,
                                                float* __restrict__ dout) {
    int blk = blockIdx.x;
    int box = blk >> 2;
    int chunk = blk & 3;
    int b = box >> 9;
    int tid = threadIdx.x;
    float* obase = dout + (size_t)box * POOL_PER_BOX + (size_t)chunk * ELEMS_PER_BLK;
    float keepf = dout[KEEP_OFF + box];
    if (keepf < 0.5f) {
        float4 z = make_float4(0.f, 0.f, 0.f, 0.f);
        float4* o4 = (float4*)obase;
        for (int i = tid; i < ELEMS_PER_BLK / 4; i += 256) o4[i] = z;
        return;
    }
    float4 bx = ((const float4*)boxes)[box];
    float w = bx.z, h = bx.w;
    float s = sqrtf(w * h);
    int lvl = (s < 112.f) ? 0 : ((s < 224.f) ? 1 : ((s < 448.f) ? 2 : 3));
    const float* feat = (lvl == 0) ? p4 : ((lvl == 1) ? p8 : ((lvl == 2) ? p16 : p32));
    int HW = 256 >> lvl;
    float inv = 1.0f / (float)(4 << lvl);
    int planesz = HW * HW;
    const float* plane0 = feat + (size_t)b * NC * planesz + (size_t)(chunk * CH_PER_BLK) * planesz;

    // uniform patch bounds (samples monotonic in t); x_lo clamped to HW-2 so c0+1 always valid
    float x1r = (bx.x - w * 0.5f) * inv;
    float bwr = w * inv / 14.0f;
    float y1r = (bx.y - h * 0.5f) * inv;
    float bhr = h * inv / 14.0f;
    float hwm1 = (float)(HW - 1);
    float xs_first = fminf(fmaxf(x1r + 0.25f * bwr, 0.0f), hwm1);
    float xs_last  = fminf(fmaxf(x1r + 13.75f * bwr, 0.0f), hwm1);
    float ys_first = fminf(fmaxf(y1r + 0.25f * bhr, 0.0f), hwm1);
    float ys_last  = fminf(fmaxf(y1r + 13.75f * bhr, 0.0f), hwm1);
    int x_lo = min((int)floorf(xs_first), HW - 2);
    int x_hi = min((int)floorf(xs_last) + 1, HW - 1);
    int y_lo = min((int)floorf(ys_first), HW - 2);
    int y_hi = min((int)floorf(ys_last) + 1, HW - 1);
    int PW = x_hi - x_lo + 1;           // >= 2
    int PH = y_hi - y_lo + 1;           // >= 2
    int cells = PW * PH;                // <= ~992 by level/area bound
    int cm1 = cells - 1;
    float invPW = 1.0f / (float)PW;
    int I = (cells + 255) >> 8;         // 1..4, block-uniform

    __shared__ float patch[2][GCH * PATCH_MAX];   // 40192 B
    __shared__ int sXc0[SS], sYoff[SS];
    __shared__ float sLX[SS], sLY[SS];

    if (tid < SS) {
        float g = (tid + 0.5f) * 0.5f;
        float xs = fminf(fmaxf(x1r + g * bwr, 0.0f), hwm1);
        int x0 = min((int)floorf(xs), HW - 2);    // clamp: lx becomes 1.0 at right edge
        sXc0[tid] = x0 - x_lo;
        sLX[tid] = xs - (float)x0;
        float ys = fminf(fmaxf(y1r + g * bhr, 0.0f), hwm1);
        int y0 = min((int)floorf(ys), HW - 2);
        sYoff[tid] = (y0 - y_lo) * PW;            // premultiplied row offset
        sLY[tid] = ys - (float)y0;
    }

    const int base_gidx = y_lo * HW + x_lo;

    // Uniform load count per wave: exactly GCH*I global_load_lds per thread, tail clamps the
    // GLOBAL index (duplicate load, harmless) while LDS dest stays dst+i (inside PATCH_MAX).
#define STAGE(gidx, bufi)                                                                   \
    do {                                                                                    \
        const float* plg_ = plane0 + (size_t)((gidx) * GCH) * planesz + base_gidx;          \
        for (int k_ = 0; k_ < I; ++k_) {                                                    \
            int i_ = tid + (k_ << 8);                                                       \
            int iq_ = min(i_, cm1);                                                         \
            int row_ = (int)(((float)iq_ + 0.5f) * invPW);                                  \
            int voff_ = row_ * (HW - PW) + iq_; /* row*HW + col, col = iq - row*PW */       \
            _Pragma("unroll")                                                               \
            for (int c_ = 0; c_ < GCH; ++c_) {                                              \
                __builtin_amdgcn_global_load_lds(                                           \
                    (GU32*)(plg_ + (size_t)c_ * planesz + voff_),                           \
                    (LU32*)(&patch[bufi][c_ * PATCH_MAX] + i_), 4, 0, 0);                   \
            }                                                                               \
        }                                                                                   \
    } while (0)

    STAGE(0, 0);

    for (int g = 0; g < NGRP; ++g) {
        if (g + 1 < NGRP) {
            STAGE(g + 1, (g + 1) & 1);
            // wait for group g's loads (and older stores); leave g+1's 4*I in flight
            switch (I) {
                case 1:  asm volatile("s_waitcnt vmcnt(4) lgkmcnt(0)" ::: "memory"); break;
                case 2:  asm volatile("s_waitcnt vmcnt(8) lgkmcnt(0)" ::: "memory"); break;
                case 3:  asm volatile("s_waitcnt vmcnt(12) lgkmcnt(0)" ::: "memory"); break;
                default: asm volatile("s_waitcnt vmcnt(16) lgkmcnt(0)" ::: "memory"); break;
            }
        } else {
            asm volatile("s_waitcnt vmcnt(0) lgkmcnt(0)" ::: "memory");
        }
        __builtin_amdgcn_s_barrier();
        asm volatile("" ::: "memory");

        const float* Pb = &patch[g & 1][0];
        float* obg = obase + g * (GCH * 196);
        for (int idx = tid; idx < GCH * 196; idx += 256) {
            int c = idx / 196;
            int p = idx - c * 196;
            int py = p / 14;
            int px = p - py * 14;
            const float* P = Pb + c * PATCH_MAX;
            int ix = px << 1, iy = py << 1;
            // adjacent-pair table reads -> ds_read2_b32 merges
            int ro0 = sYoff[iy],  ro1 = sYoff[iy + 1];
            float ly0 = sLY[iy],  ly1 = sLY[iy + 1];
            int c00 = sXc0[ix],   c01 = sXc0[ix + 1];
            float lx0 = sLX[ix],  lx1 = sLX[ix + 1];
            float acc = 0.f;
#define SAMPLE(RO, LY, CC, LX)                                        \
            {                                                         \
                const float* q_ = P + (RO) + (CC);                    \
                float f00 = q_[0], f01 = q_[1];                       \
                const float* q2_ = q_ + PW;                           \
                float f10 = q2_[0], f11 = q2_[1];                     \
                float top = f00 + (LX) * (f01 - f00);                 \
                float bot = f10 + (LX) * (f11 - f10);                 \
                acc += top + (LY) * (bot - top);                      \
            }
            SAMPLE(ro0, ly0, c00, lx0)
            SAMPLE(ro0, ly0, c01, lx1)
            SAMPLE(ro1, ly1, c00, lx0)
            SAMPLE(ro1, ly1, c01, lx1)
#undef SAMPLE
            obg[idx] = acc * 0.25f;
        }

        if (g + 1 < NGRP) {
            asm volatile("" ::: "memory");
            __builtin_amdgcn_s_barrier();   // all waves done reading buf before it's restaged
            asm volatile("" ::: "memory");
        }
    }
#undef STAGE
}

extern "C" void kernel_launch(void* const* d_in, const int* in_sizes, int n_in,
                              void* d_out, int out_size, void* d_ws, size_t ws_size,
                              hipStream_t stream) {
    const float* p4 = (const float*)d_in[0];
    const float* p8 = (const float*)d_in[1];
    const float* p16 = (const float*)d_in[2];
    const float* p32 = (const float*)d_in[3];
    const float* boxes = (const float*)d_in[4];
    const float* scores = (const float*)d_in[5];
    float* out = (float*)d_out;

    k_nms<<<NB, NN, 0, stream>>>(boxes, scores, out);
    k_roi<<<NB * NN * CH_SPLIT, 256, 0, stream>>>(p4, p8, p16, p32, boxes, out);
}